// Round 14
// baseline (103.559 us; speedup 1.0000x reference)
//
#include <hip/hip_runtime.h>

#define NN 50000
#define NE 800000
#define D 64
#define BN_SH 8
#define BNODES 256
#define NB 196                              // buckets of 256 dst nodes
#define EPB 4096
#define NWB 196                             // edge-chunk blocks (196*4096 >= NE)
#define CONV_B 800                          // feat->bf16 convert blocks
#define BCAP 4608                           // per-bucket region capacity (mean 4081 + 8 sigma)

// ---- workspace layout (~31 MB) ----
constexpr size_t alignup(size_t x) { return (x + 1023) & ~size_t(1023); }
constexpr size_t OFF_EM   = 0;                                         // NB*BCAP*8 = 7.2 MB
constexpr size_t OFF_EM2  = alignup(OFF_EM + (size_t)NB * BCAP * 8);   // NB*BCAP*4 = 3.6 MB
constexpr size_t OFF_AGG  = alignup(OFF_EM2 + (size_t)NB * BCAP * 4);  // NN*D*4 = 12.8 MB
constexpr size_t OFF_FBLO = alignup(OFF_AGG + (size_t)NN * D * 4);     // NN*32*2 = 3.2 MB
constexpr size_t OFF_FBHI = alignup(OFF_FBLO + (size_t)NN * 32 * 2);   // NN*32*2 = 3.2 MB
constexpr size_t OFF_RS2  = alignup(OFF_FBHI + (size_t)NN * 32 * 2);   // NN int2 = 400 KB
constexpr size_t OFF_CUR  = alignup(OFF_RS2 + (size_t)NN * 8);         // NB i32

__device__ __forceinline__ unsigned f2bf(unsigned u) {   // f32 bits -> bf16 bits, RNE
    return (u + 0x7FFFu + ((u >> 16) & 1u)) >> 16;
}
__device__ __forceinline__ float bfu(unsigned short h) { // bf16 bits -> f32
    return __uint_as_float((unsigned)h << 16);
}

// K0: zero bucket cursors
__global__ __launch_bounds__(256) void gc_zero(int* cur) {
    if (threadIdx.x < NB) cur[threadIdx.x] = 0;
}

// K1: blocks [0,NWB): binned edge write into fixed per-bucket regions with
// per-block bulk atomic reservation. blocks [NWB, NWB+CONV_B): feat -> bf16
// convert into TWO contiguous half-tables (channels 0-31 -> fbLO, 32-63 ->
// fbHI), each 3.2 MB so a gather pass's working set fits a 4 MB XCD L2.
// rec = { src | dst_local<<16 , bits(ew) }
__global__ __launch_bounds__(256) void bin_write(const int* __restrict__ src,
                                                 const int* __restrict__ dst,
                                                 const float* __restrict__ ew,
                                                 const float* __restrict__ feat,
                                                 int* __restrict__ cur,
                                                 uint2* __restrict__ em,
                                                 ushort* __restrict__ fbLO,
                                                 ushort* __restrict__ fbHI) {
    int b = blockIdx.x;
    if (b >= NWB) {
        int cb = b - NWB;
        const float4* f4 = (const float4*)feat;
        for (int i = cb * 256 + threadIdx.x; i < NN * D / 4; i += CONV_B * 256) {
            float4 v = f4[i];
            ushort4 o;
            o.x = (ushort)f2bf(__float_as_uint(v.x));
            o.y = (ushort)f2bf(__float_as_uint(v.y));
            o.z = (ushort)f2bf(__float_as_uint(v.z));
            o.w = (ushort)f2bf(__float_as_uint(v.w));
            int n = i >> 4;           // 16 float4-chunks per node
            int c = i & 15;           // channel quad 4c..4c+3
            ushort* tp = (c < 8) ? (fbLO + n * 32 + (c << 2))
                                 : (fbHI + n * 32 + ((c - 8) << 2));
            *(ushort4*)tp = o;
        }
        return;
    }
    __shared__ int h[NB];
    __shared__ int gb[NB];
    for (int i = threadIdx.x; i < NB; i += 256) h[i] = 0;
    __syncthreads();
    int c0 = b * EPB;
    uint2 rec[16];
    int rk[16];
    int bk[16];
#pragma unroll
    for (int j = 0; j < 16; ++j) {
        int e = c0 + j * 256 + threadIdx.x;
        if (e < NE) {
            int dv = dst[e];
            int bb = dv >> BN_SH;
            bk[j] = bb;
            rk[j] = atomicAdd(&h[bb], 1);
            rec[j] = make_uint2((unsigned)src[e] | ((unsigned)(dv & (BNODES - 1)) << 16),
                                __float_as_uint(ew[e]));
        } else bk[j] = -1;
    }
    __syncthreads();
    for (int i = threadIdx.x; i < NB; i += 256) {
        int c = h[i];
        gb[i] = c ? atomicAdd(&cur[i], c) : 0;
    }
    __syncthreads();
#pragma unroll
    for (int j = 0; j < 16; ++j)
        if (bk[j] >= 0)
            em[(size_t)bk[j] * BCAP + gb[bk[j]] + rk[j]] = rec[j];
}

// K2: per-bucket counting sort -> per-node {beg,end} runs (rs2); em2 packed
// to 4 B: { src:16 | bf16(w):16 }. All writes stay in the block's own region.
__global__ __launch_bounds__(256) void bucket_csr(const uint2* __restrict__ em,
                                                  const int* __restrict__ cur,
                                                  int2* __restrict__ rs2,
                                                  unsigned* __restrict__ em2) {
    __shared__ int hist[BNODES];
    __shared__ int lbase[BNODES];
    __shared__ int lcur[BNODES];
    __shared__ int sh[BNODES];
    int b = blockIdx.x;
    int t = threadIdx.x;
    int beg = b * BCAP;
    int end = beg + cur[b];
    hist[t] = 0;
    __syncthreads();
    for (int e = beg + t; e < end; e += 256)
        atomicAdd(&hist[(em[e].x >> 16) & 0xFFu], 1);
    __syncthreads();
    int v = hist[t];
    sh[t] = v;
    __syncthreads();
    for (int o = 1; o < 256; o <<= 1) {
        int x = (t >= o) ? sh[t - o] : 0;
        __syncthreads();
        sh[t] += x;
        __syncthreads();
    }
    int ex = sh[t] - v;
    lbase[t] = ex;
    lcur[t] = 0;
    int n = (b << BN_SH) + t;
    if (n < NN) rs2[n] = make_int2(beg + ex, beg + ex + v);
    __syncthreads();
    for (int e = beg + t; e < end; e += 256) {
        uint2 r = em[e];
        unsigned dl = (r.x >> 16) & 0xFFu;
        int pos = beg + lbase[dl] + atomicAdd(&lcur[dl], 1);
        em2[pos] = (r.x & 0xFFFFu) | (f2bf(r.y) << 16);
    }
}

// K3: gather over ONE half-table (32 channels, 64 B rows, 3.2 MB -> fits a
// 4 MB XCD L2). Wave per node; 4 edge-groups x 16 lanes; lane s holds
// channels 2s,2s+1 (ushort2 load). Per 8 edges: 2 uniform em2 reads + 2
// row-load instructions. Butterfly over lane bits 4,5 combines group
// partials; lanes 0-15 write float2 to their half of the agg row.
__global__ __launch_bounds__(256) void gc_gather_half(const ushort* __restrict__ fbH,
                                                      const int2* __restrict__ rs2,
                                                      const unsigned* __restrict__ em2,
                                                      float* __restrict__ agg,
                                                      int half) {
    int wid = threadIdx.x >> 6;
    int lane = threadIdx.x & 63;
    int g = lane >> 4;          // edge group 0..3
    int s = lane & 15;          // channel pair: 2s, 2s+1
    int n = blockIdx.x * 4 + wid;
    if (n >= NN) return;
    int2 r2 = rs2[n];
    int beg = __builtin_amdgcn_readfirstlane(r2.x);
    int end = __builtin_amdgcn_readfirstlane(r2.y);
    float a0 = 0.f, a1 = 0.f;
    int e = beg;
    for (; e + 8 <= end; e += 8) {                   // 2 chunks in flight
        unsigned ra = em2[e + g];
        unsigned rb = em2[e + 4 + g];
        ushort2 qa = *(const ushort2*)(fbH + ((ra & 0xFFFFu) << 5) + (s << 1));
        ushort2 qb = *(const ushort2*)(fbH + ((rb & 0xFFFFu) << 5) + (s << 1));
        float wa = __uint_as_float(ra & 0xFFFF0000u);
        float wb = __uint_as_float(rb & 0xFFFF0000u);
        a0 = fmaf(wa, bfu(qa.x), a0);
        a1 = fmaf(wa, bfu(qa.y), a1);
        a0 = fmaf(wb, bfu(qb.x), a0);
        a1 = fmaf(wb, bfu(qb.y), a1);
    }
    for (; e + 4 <= end; e += 4) {
        unsigned r = em2[e + g];
        ushort2 q = *(const ushort2*)(fbH + ((r & 0xFFFFu) << 5) + (s << 1));
        float w = __uint_as_float(r & 0xFFFF0000u);
        a0 = fmaf(w, bfu(q.x), a0);
        a1 = fmaf(w, bfu(q.y), a1);
    }
    if (e < end) {                                    // tail: m in 1..3
        int m = end - e;
        if (g < m) {
            unsigned r = em2[e + g];
            ushort2 q = *(const ushort2*)(fbH + ((r & 0xFFFFu) << 5) + (s << 1));
            float w = __uint_as_float(r & 0xFFFF0000u);
            a0 = fmaf(w, bfu(q.x), a0);
            a1 = fmaf(w, bfu(q.y), a1);
        }
    }
    // combine the 4 group-partials (lane bits 4 and 5)
    a0 += __shfl_xor(a0, 16); a1 += __shfl_xor(a1, 16);
    a0 += __shfl_xor(a0, 32); a1 += __shfl_xor(a1, 32);
    if (g == 0)
        ((float2*)(agg + (size_t)n * D + half * 32))[s] = make_float2(a0, a1);
}

// K4: epilogue GEMM (identical to the round-8 known-good version):
// C[N,64] = [agg | feat] @ [Wn ; Ws^T] + bn.
#define BM 128
__global__ __launch_bounds__(256) void gemm_out(const float* __restrict__ agg,
                                                const float* __restrict__ feat,
                                                const float* __restrict__ Wn,
                                                const float* __restrict__ Ws,
                                                const float* __restrict__ bn,
                                                float* __restrict__ out) {
    __shared__ float Bs[128 * 64];   // 32 KB: Bs[k*64+d]
    __shared__ float As[BM * 36];    // 18 KB, stride 36
    int tid = threadIdx.x;
    for (int i = tid; i < 128 * 64; i += 256) {
        int k = i >> 6, d = i & 63;
        Bs[i] = (k < 64) ? Wn[i] : Ws[d * 64 + (k - 64)];
    }
    int tn = tid & 7;
    int tm = tid >> 3;
    float4 blo = *(const float4*)&bn[tn * 8];
    float4 bhi = *(const float4*)&bn[tn * 8 + 4];
    float acc[4][8];
#pragma unroll
    for (int i = 0; i < 4; ++i) {
        acc[i][0] = blo.x; acc[i][1] = blo.y; acc[i][2] = blo.z; acc[i][3] = blo.w;
        acc[i][4] = bhi.x; acc[i][5] = bhi.y; acc[i][6] = bhi.z; acc[i][7] = bhi.w;
    }
    int n0 = blockIdx.x * BM;
    for (int c = 0; c < 4; ++c) {
        const float* Asrc = (c < 2) ? agg : feat;
        int ksrc = (c & 1) * 32;
        __syncthreads();
        for (int i = tid; i < BM * 8; i += 256) {
            int r = i >> 3, c4 = i & 7;
            int nrow = n0 + r;
            const float* p = Asrc + (size_t)(nrow < NN ? nrow : 0) * 64 + ksrc + c4 * 4;
            float4 v = *(const float4*)p;
            float* q = &As[r * 36 + c4 * 4];
            q[0] = v.x; q[1] = v.y; q[2] = v.z; q[3] = v.w;
        }
        __syncthreads();
        int kb = c * 32;
#pragma unroll
        for (int k4 = 0; k4 < 8; ++k4) {
            float4 av[4];
#pragma unroll
            for (int i = 0; i < 4; ++i)
                av[i] = *(const float4*)&As[(tm + 32 * i) * 36 + k4 * 4];
#pragma unroll
            for (int kk = 0; kk < 4; ++kk) {
                int k = kb + k4 * 4 + kk;
                float4 wlo = *(const float4*)&Bs[k * 64 + tn * 8];
                float4 whi = *(const float4*)&Bs[k * 64 + tn * 8 + 4];
#pragma unroll
                for (int i = 0; i < 4; ++i) {
                    float a = (kk == 0) ? av[i].x : (kk == 1) ? av[i].y
                            : (kk == 2) ? av[i].z : av[i].w;
                    acc[i][0] = fmaf(a, wlo.x, acc[i][0]);
                    acc[i][1] = fmaf(a, wlo.y, acc[i][1]);
                    acc[i][2] = fmaf(a, wlo.z, acc[i][2]);
                    acc[i][3] = fmaf(a, wlo.w, acc[i][3]);
                    acc[i][4] = fmaf(a, whi.x, acc[i][4]);
                    acc[i][5] = fmaf(a, whi.y, acc[i][5]);
                    acc[i][6] = fmaf(a, whi.z, acc[i][6]);
                    acc[i][7] = fmaf(a, whi.w, acc[i][7]);
                }
            }
        }
    }
#pragma unroll
    for (int i = 0; i < 4; ++i) {
        int r = n0 + tm + 32 * i;
        if (r < NN) {
            float* p = &out[(size_t)r * 64 + tn * 8];
            *(float4*)p = make_float4(acc[i][0], acc[i][1], acc[i][2], acc[i][3]);
            *(float4*)(p + 4) = make_float4(acc[i][4], acc[i][5], acc[i][6], acc[i][7]);
        }
    }
}

extern "C" void kernel_launch(void* const* d_in, const int* in_sizes, int n_in,
                              void* d_out, int out_size, void* d_ws, size_t ws_size,
                              hipStream_t stream) {
    const float* feat = (const float*)d_in[0];
    const int*   src  = (const int*)d_in[1];
    const int*   dst  = (const int*)d_in[2];
    const float* ew   = (const float*)d_in[3];
    const float* Wn   = (const float*)d_in[4];
    const float* bn   = (const float*)d_in[5];
    const float* Ws   = (const float*)d_in[6];
    float* out = (float*)d_out;

    char* ws = (char*)d_ws;
    uint2*    em   = (uint2*)(ws + OFF_EM);
    unsigned* em2  = (unsigned*)(ws + OFF_EM2);
    float*    agg  = (float*)(ws + OFF_AGG);
    ushort*   fbLO = (ushort*)(ws + OFF_FBLO);
    ushort*   fbHI = (ushort*)(ws + OFF_FBHI);
    int2*     rs2  = (int2*)(ws + OFF_RS2);
    int*      cur  = (int*)(ws + OFF_CUR);

    gc_zero<<<1, 256, 0, stream>>>(cur);
    bin_write<<<NWB + CONV_B, 256, 0, stream>>>(src, dst, ew, feat, cur, em, fbLO, fbHI);
    bucket_csr<<<NB, 256, 0, stream>>>(em, cur, rs2, em2);
    gc_gather_half<<<(NN + 3) / 4, 256, 0, stream>>>(fbLO, rs2, em2, agg, 0);
    gc_gather_half<<<(NN + 3) / 4, 256, 0, stream>>>(fbHI, rs2, em2, agg, 1);
    gemm_out<<<(NN + BM - 1) / BM, 256, 0, stream>>>(agg, feat, Wn, Ws, bn, out);
}

// Round 16
// 71.234 us; speedup vs baseline: 1.4538x; 1.4538x over previous
//
#include <hip/hip_runtime.h>

#define NN 50000
#define NE 800000
#define D 64
#define BN_SH 8
#define BNODES 256
#define NB 196                              // buckets of 256 dst nodes
#define EPB 4096
#define NWB 196                             // edge-chunk blocks (196*4096 >= NE)
#define CONV_B 800                          // feat->bf16 convert blocks
#define BCAP 4608                           // per-bucket region capacity (mean 4081 + 8 sigma)

// ---- workspace layout (~24 MB) ----
constexpr size_t alignup(size_t x) { return (x + 1023) & ~size_t(1023); }
constexpr size_t OFF_EM   = 0;                                         // NB*BCAP*8 = 7.2 MB
constexpr size_t OFF_EM2  = alignup(OFF_EM + (size_t)NB * BCAP * 8);   // NB*BCAP*4 = 3.6 MB
constexpr size_t OFF_AGGB = alignup(OFF_EM2 + (size_t)NB * BCAP * 4);  // NN*64*2 = 6.4 MB (bf16)
constexpr size_t OFF_FB   = alignup(OFF_AGGB + (size_t)NN * D * 2);    // NN*64*2 = 6.4 MB (bf16)
constexpr size_t OFF_RS2  = alignup(OFF_FB + (size_t)NN * D * 2);      // NN int2 = 400 KB
constexpr size_t OFF_CUR  = alignup(OFF_RS2 + (size_t)NN * 8);         // NB i32

typedef __attribute__((ext_vector_type(8))) short short8v;   // 8 x bf16 (4 VGPRs)
typedef __attribute__((ext_vector_type(4))) float float4v;   // 4 x f32 acc

__device__ __forceinline__ unsigned f2bf(unsigned u) {   // f32 bits -> bf16 bits, RNE
    return (u + 0x7FFFu + ((u >> 16) & 1u)) >> 16;
}
__device__ __forceinline__ float bfu(unsigned short h) { // bf16 bits -> f32
    return __uint_as_float((unsigned)h << 16);
}

// K0: zero bucket cursors
__global__ __launch_bounds__(256) void gc_zero(int* cur) {
    if (threadIdx.x < NB) cur[threadIdx.x] = 0;
}

// K1: blocks [0,NWB): binned edge write into fixed per-bucket regions with
// per-block bulk atomic reservation. blocks [NWB, NWB+CONV_B): feat -> bf16.
// rec = { src | dst_local<<16 , bits(ew) }
__global__ __launch_bounds__(256) void bin_write(const int* __restrict__ src,
                                                 const int* __restrict__ dst,
                                                 const float* __restrict__ ew,
                                                 const float* __restrict__ feat,
                                                 int* __restrict__ cur,
                                                 uint2* __restrict__ em,
                                                 ushort* __restrict__ fb16) {
    int b = blockIdx.x;
    if (b >= NWB) {
        int cb = b - NWB;
        const float4* f4 = (const float4*)feat;
        ushort4* o4 = (ushort4*)fb16;
        for (int i = cb * 256 + threadIdx.x; i < NN * D / 4; i += CONV_B * 256) {
            float4 v = f4[i];
            ushort4 o;
            o.x = (ushort)f2bf(__float_as_uint(v.x));
            o.y = (ushort)f2bf(__float_as_uint(v.y));
            o.z = (ushort)f2bf(__float_as_uint(v.z));
            o.w = (ushort)f2bf(__float_as_uint(v.w));
            o4[i] = o;
        }
        return;
    }
    __shared__ int h[NB];
    __shared__ int gb[NB];
    for (int i = threadIdx.x; i < NB; i += 256) h[i] = 0;
    __syncthreads();
    int c0 = b * EPB;
    uint2 rec[16];
    int rk[16];
    int bk[16];
#pragma unroll
    for (int j = 0; j < 16; ++j) {
        int e = c0 + j * 256 + threadIdx.x;
        if (e < NE) {
            int dv = dst[e];
            int bb = dv >> BN_SH;
            bk[j] = bb;
            rk[j] = atomicAdd(&h[bb], 1);
            rec[j] = make_uint2((unsigned)src[e] | ((unsigned)(dv & (BNODES - 1)) << 16),
                                __float_as_uint(ew[e]));
        } else bk[j] = -1;
    }
    __syncthreads();
    for (int i = threadIdx.x; i < NB; i += 256) {
        int c = h[i];
        gb[i] = c ? atomicAdd(&cur[i], c) : 0;
    }
    __syncthreads();
#pragma unroll
    for (int j = 0; j < 16; ++j)
        if (bk[j] >= 0)
            em[(size_t)bk[j] * BCAP + gb[bk[j]] + rk[j]] = rec[j];
}

// K2: per-bucket counting sort -> per-node {beg,end} runs (rs2); em2 packed
// to 4 B: { src:16 | bf16(w):16 }. All writes stay in the block's own region.
__global__ __launch_bounds__(256) void bucket_csr(const uint2* __restrict__ em,
                                                  const int* __restrict__ cur,
                                                  int2* __restrict__ rs2,
                                                  unsigned* __restrict__ em2) {
    __shared__ int hist[BNODES];
    __shared__ int lbase[BNODES];
    __shared__ int lcur[BNODES];
    __shared__ int sh[BNODES];
    int b = blockIdx.x;
    int t = threadIdx.x;
    int beg = b * BCAP;
    int end = beg + cur[b];
    hist[t] = 0;
    __syncthreads();
    for (int e = beg + t; e < end; e += 256)
        atomicAdd(&hist[(em[e].x >> 16) & 0xFFu], 1);
    __syncthreads();
    int v = hist[t];
    sh[t] = v;
    __syncthreads();
    for (int o = 1; o < 256; o <<= 1) {
        int x = (t >= o) ? sh[t - o] : 0;
        __syncthreads();
        sh[t] += x;
        __syncthreads();
    }
    int ex = sh[t] - v;
    lbase[t] = ex;
    lcur[t] = 0;
    int n = (b << BN_SH) + t;
    if (n < NN) rs2[n] = make_int2(beg + ex, beg + ex + v);
    __syncthreads();
    for (int e = beg + t; e < end; e += 256) {
        uint2 r = em[e];
        unsigned dl = (r.x >> 16) & 0xFFu;
        int pos = beg + lbase[dl] + atomicAdd(&lcur[dl], 1);
        em2[pos] = (r.x & 0xFFFFu) | (f2bf(r.y) << 16);
    }
}

// K3: gather — round-10 structure (one wave per node, 8-deep unrolled, the
// measured best), output now bf16 (halves the write, feeds MFMA A directly).
__global__ __launch_bounds__(256) void gc_gather(const ushort* __restrict__ fb16,
                                                 const int2* __restrict__ rs2,
                                                 const unsigned* __restrict__ em2,
                                                 ushort* __restrict__ aggb) {
    int wid = threadIdx.x >> 6;
    int lane = threadIdx.x & 63;
    int n = blockIdx.x * 4 + wid;
    if (n >= NN) return;
    int2 r2 = rs2[n];
    int beg = __builtin_amdgcn_readfirstlane(r2.x);
    int end = __builtin_amdgcn_readfirstlane(r2.y);
    float acc = 0.f;
    int e = beg;
    for (; e + 8 <= end; e += 8) {
        unsigned v[8];
#pragma unroll
        for (int j = 0; j < 8; ++j) v[j] = em2[e + j];
        float f[8];
#pragma unroll
        for (int j = 0; j < 8; ++j)
            f[j] = bfu(fb16[(size_t)(v[j] & 0xFFFFu) * D + lane]);
#pragma unroll
        for (int j = 0; j < 8; ++j)
            acc = fmaf(__uint_as_float(v[j] & 0xFFFF0000u), f[j], acc);
    }
    for (; e + 4 <= end; e += 4) {
        unsigned v0 = em2[e], v1 = em2[e + 1], v2 = em2[e + 2], v3 = em2[e + 3];
        float f0 = bfu(fb16[(size_t)(v0 & 0xFFFFu) * D + lane]);
        float f1 = bfu(fb16[(size_t)(v1 & 0xFFFFu) * D + lane]);
        float f2 = bfu(fb16[(size_t)(v2 & 0xFFFFu) * D + lane]);
        float f3 = bfu(fb16[(size_t)(v3 & 0xFFFFu) * D + lane]);
        acc = fmaf(__uint_as_float(v0 & 0xFFFF0000u), f0, acc);
        acc = fmaf(__uint_as_float(v1 & 0xFFFF0000u), f1, acc);
        acc = fmaf(__uint_as_float(v2 & 0xFFFF0000u), f2, acc);
        acc = fmaf(__uint_as_float(v3 & 0xFFFF0000u), f3, acc);
    }
    for (; e < end; ++e) {
        unsigned v = em2[e];
        float f = bfu(fb16[(size_t)(v & 0xFFFFu) * D + lane]);
        acc = fmaf(__uint_as_float(v & 0xFFFF0000u), f, acc);
    }
    aggb[(size_t)n * D + lane] = (ushort)f2bf(__float_as_uint(acc));
}

// K4: MFMA epilogue: C[N,64] = [aggb | fb16] @ [Wn ; Ws^T] + bn, bf16 inputs,
// f32 accumulate. Block = 128 rows, 4 waves; wave w owns rows [w*32, w*32+32).
// A-frags load straight from global (16 B/lane). B staged bf16-transposed in
// LDS: Bt[col][k], stride 136 (2-way bank alias only). Layouts per cdna4_isa
// §10 + m89: A row=lane&15, k=(lane>>4)*8+j; B col=lane&15, same k;
// C col=lane&15, row=(lane>>4)*4+reg.
__global__ __launch_bounds__(256) void gemm_mfma(const ushort* __restrict__ aggb,
                                                 const ushort* __restrict__ fb16,
                                                 const float* __restrict__ Wn,
                                                 const float* __restrict__ Ws,
                                                 const float* __restrict__ bn,
                                                 float* __restrict__ out) {
    __shared__ ushort Bt[64 * 136];   // 17.4 KB
    int tid = threadIdx.x;
    for (int i = tid; i < 64 * 128; i += 256) {
        int col = i & 63, k = i >> 6;
        float v = (k < 64) ? Wn[k * 64 + col] : Ws[col * 64 + (k - 64)];
        Bt[col * 136 + k] = (ushort)f2bf(__float_as_uint(v));
    }
    __syncthreads();
    int w = tid >> 6, lane = tid & 63;
    int lr = lane & 15;       // A-row / B-col / C-col within tile
    int lk = lane >> 4;       // k-subchunk 0..3
    int n0 = blockIdx.x * 128 + w * 32;
    float4v acc[2][4];
#pragma unroll
    for (int c = 0; c < 4; ++c) {
        float bv = bn[c * 16 + lr];
        acc[0][c] = (float4v){bv, bv, bv, bv};
        acc[1][c] = (float4v){bv, bv, bv, bv};
    }
    int r0 = min(n0 + lr, NN - 1);
    int r1 = min(n0 + 16 + lr, NN - 1);
#pragma unroll
    for (int kc = 0; kc < 4; ++kc) {
        const ushort* At = (kc < 2) ? aggb : fb16;
        int bk = (kc & 1) * 32 + lk * 8;       // k offset within the 64-wide table
        short8v a0 = *(const short8v*)(At + (size_t)r0 * 64 + bk);
        short8v a1 = *(const short8v*)(At + (size_t)r1 * 64 + bk);
        int kg = kc * 32 + lk * 8;             // k offset within Bt's 128
#pragma unroll
        for (int c = 0; c < 4; ++c) {
            short8v bf = *(const short8v*)(&Bt[(c * 16 + lr) * 136 + kg]);
            acc[0][c] = __builtin_amdgcn_mfma_f32_16x16x32_bf16(a0, bf, acc[0][c], 0, 0, 0);
            acc[1][c] = __builtin_amdgcn_mfma_f32_16x16x32_bf16(a1, bf, acc[1][c], 0, 0, 0);
        }
    }
#pragma unroll
    for (int r = 0; r < 2; ++r) {
        int rowb = n0 + r * 16 + lk * 4;
#pragma unroll
        for (int c = 0; c < 4; ++c) {
            int col = c * 16 + lr;
#pragma unroll
            for (int j = 0; j < 4; ++j) {
                int row = rowb + j;
                if (row < NN) out[(size_t)row * 64 + col] = acc[r][c][j];
            }
        }
    }
}

extern "C" void kernel_launch(void* const* d_in, const int* in_sizes, int n_in,
                              void* d_out, int out_size, void* d_ws, size_t ws_size,
                              hipStream_t stream) {
    const float* feat = (const float*)d_in[0];
    const int*   src  = (const int*)d_in[1];
    const int*   dst  = (const int*)d_in[2];
    const float* ew   = (const float*)d_in[3];
    const float* Wn   = (const float*)d_in[4];
    const float* bn   = (const float*)d_in[5];
    const float* Ws   = (const float*)d_in[6];
    float* out = (float*)d_out;

    char* ws = (char*)d_ws;
    uint2*    em   = (uint2*)(ws + OFF_EM);
    unsigned* em2  = (unsigned*)(ws + OFF_EM2);
    ushort*   aggb = (ushort*)(ws + OFF_AGGB);
    ushort*   fb16 = (ushort*)(ws + OFF_FB);
    int2*     rs2  = (int2*)(ws + OFF_RS2);
    int*      cur  = (int*)(ws + OFF_CUR);

    gc_zero<<<1, 256, 0, stream>>>(cur);
    bin_write<<<NWB + CONV_B, 256, 0, stream>>>(src, dst, ew, feat, cur, em, fb16);
    bucket_csr<<<NB, 256, 0, stream>>>(em, cur, rs2, em2);
    gc_gather<<<(NN + 3) / 4, 256, 0, stream>>>(fb16, rs2, em2, aggb);
    gemm_mfma<<<(NN + 127) / 128, 256, 0, stream>>>(aggb, fb16, Wn, Ws, bn, out);
}

// Round 17
// 67.646 us; speedup vs baseline: 1.5309x; 1.0530x over previous
//
#include <hip/hip_runtime.h>

#define NN 50000
#define NE 800000
#define D 64
#define BN_SH 8
#define BNODES 256
#define NB 196                              // buckets of 256 dst nodes
#define EPB 4096
#define NWB 196                             // edge-chunk blocks (196*4096 >= NE)
#define CONV_B 800                          // feat->bf16 convert blocks
#define BCAP 4608                           // per-bucket region capacity (mean 4081 + 8 sigma)

// ---- workspace layout (~24 MB) ----
constexpr size_t alignup(size_t x) { return (x + 1023) & ~size_t(1023); }
constexpr size_t OFF_EM   = 0;                                         // NB*BCAP*8 = 7.2 MB
constexpr size_t OFF_EM2  = alignup(OFF_EM + (size_t)NB * BCAP * 8);   // NB*BCAP*4 = 3.6 MB
constexpr size_t OFF_AGGB = alignup(OFF_EM2 + (size_t)NB * BCAP * 4);  // NN*64*2 = 6.4 MB (bf16)
constexpr size_t OFF_FB   = alignup(OFF_AGGB + (size_t)NN * D * 2);    // NN*64*2 = 6.4 MB (bf16)
constexpr size_t OFF_RS2  = alignup(OFF_FB + (size_t)NN * D * 2);      // NN int2 = 400 KB
constexpr size_t OFF_CUR  = alignup(OFF_RS2 + (size_t)NN * 8);         // NB i32

typedef __attribute__((ext_vector_type(8))) short short8v;   // 8 x bf16 (4 VGPRs)
typedef __attribute__((ext_vector_type(4))) float float4v;   // 4 x f32 acc

__device__ __forceinline__ unsigned f2bf(unsigned u) {   // f32 bits -> bf16 bits, RNE
    return (u + 0x7FFFu + ((u >> 16) & 1u)) >> 16;
}
__device__ __forceinline__ float bfu(unsigned short h) { // bf16 bits -> f32
    return __uint_as_float((unsigned)h << 16);
}

// K0: zero bucket cursors
__global__ __launch_bounds__(256) void gc_zero(int* cur) {
    if (threadIdx.x < NB) cur[threadIdx.x] = 0;
}

// K1: blocks [0,NWB): binned edge write into fixed per-bucket regions with
// per-block bulk atomic reservation. blocks [NWB, NWB+CONV_B): feat -> bf16.
// rec = { src | dst_local<<16 , bits(ew) }
__global__ __launch_bounds__(256) void bin_write(const int* __restrict__ src,
                                                 const int* __restrict__ dst,
                                                 const float* __restrict__ ew,
                                                 const float* __restrict__ feat,
                                                 int* __restrict__ cur,
                                                 uint2* __restrict__ em,
                                                 ushort* __restrict__ fb16) {
    int b = blockIdx.x;
    if (b >= NWB) {
        int cb = b - NWB;
        const float4* f4 = (const float4*)feat;
        ushort4* o4 = (ushort4*)fb16;
        for (int i = cb * 256 + threadIdx.x; i < NN * D / 4; i += CONV_B * 256) {
            float4 v = f4[i];
            ushort4 o;
            o.x = (ushort)f2bf(__float_as_uint(v.x));
            o.y = (ushort)f2bf(__float_as_uint(v.y));
            o.z = (ushort)f2bf(__float_as_uint(v.z));
            o.w = (ushort)f2bf(__float_as_uint(v.w));
            o4[i] = o;
        }
        return;
    }
    __shared__ int h[NB];
    __shared__ int gb[NB];
    for (int i = threadIdx.x; i < NB; i += 256) h[i] = 0;
    __syncthreads();
    int c0 = b * EPB;
    uint2 rec[16];
    int rk[16];
    int bk[16];
#pragma unroll
    for (int j = 0; j < 16; ++j) {
        int e = c0 + j * 256 + threadIdx.x;
        if (e < NE) {
            int dv = dst[e];
            int bb = dv >> BN_SH;
            bk[j] = bb;
            rk[j] = atomicAdd(&h[bb], 1);
            rec[j] = make_uint2((unsigned)src[e] | ((unsigned)(dv & (BNODES - 1)) << 16),
                                __float_as_uint(ew[e]));
        } else bk[j] = -1;
    }
    __syncthreads();
    for (int i = threadIdx.x; i < NB; i += 256) {
        int c = h[i];
        gb[i] = c ? atomicAdd(&cur[i], c) : 0;
    }
    __syncthreads();
#pragma unroll
    for (int j = 0; j < 16; ++j)
        if (bk[j] >= 0)
            em[(size_t)bk[j] * BCAP + gb[bk[j]] + rk[j]] = rec[j];
}

// K2: per-bucket counting sort, LDS-staged single-pass: coalesced-load the
// bucket's records into LDS once, histogram/scan/scatter in LDS, then write
// em2 out fully coalesced ascending. Also emits per-node {beg,end} (rs2).
// em2 record: { src:16 | bf16(w):16 }.
__global__ __launch_bounds__(256) void bucket_csr(const uint2* __restrict__ em,
                                                  const int* __restrict__ cur,
                                                  int2* __restrict__ rs2,
                                                  unsigned* __restrict__ em2) {
    __shared__ uint2 buf[BCAP];        // 36.8 KB raw records
    __shared__ unsigned obuf[BCAP];    // 18.4 KB sorted packed records
    __shared__ int hist[BNODES];
    __shared__ int lbase[BNODES];
    __shared__ int lcur[BNODES];
    __shared__ int sh[BNODES];
    int b = blockIdx.x;
    int t = threadIdx.x;
    int beg = b * BCAP;
    int cnt = cur[b];
    hist[t] = 0;
    __syncthreads();
    // coalesced global->LDS load of the bucket's records + LDS histogram
    for (int i = t; i < cnt; i += 256) {
        uint2 r = em[beg + i];
        buf[i] = r;
        atomicAdd(&hist[(r.x >> 16) & 0xFFu], 1);
    }
    __syncthreads();
    int v = hist[t];
    sh[t] = v;
    __syncthreads();
    for (int o = 1; o < 256; o <<= 1) {
        int x = (t >= o) ? sh[t - o] : 0;
        __syncthreads();
        sh[t] += x;
        __syncthreads();
    }
    int ex = sh[t] - v;
    lbase[t] = ex;
    lcur[t] = 0;
    int n = (b << BN_SH) + t;
    if (n < NN) rs2[n] = make_int2(beg + ex, beg + ex + v);
    __syncthreads();
    // scatter within LDS (random LDS writes), then coalesced global write
    for (int i = t; i < cnt; i += 256) {
        uint2 r = buf[i];
        unsigned dl = (r.x >> 16) & 0xFFu;
        int pos = lbase[dl] + atomicAdd(&lcur[dl], 1);
        obuf[pos] = (r.x & 0xFFFFu) | (f2bf(r.y) << 16);
    }
    __syncthreads();
    for (int i = t; i < cnt; i += 256)
        em2[beg + i] = obuf[i];
}

// K3: gather — round-10 structure (one wave per node, 8-deep unrolled, the
// measured best), output bf16 (halves the write, feeds MFMA A directly).
__global__ __launch_bounds__(256) void gc_gather(const ushort* __restrict__ fb16,
                                                 const int2* __restrict__ rs2,
                                                 const unsigned* __restrict__ em2,
                                                 ushort* __restrict__ aggb) {
    int wid = threadIdx.x >> 6;
    int lane = threadIdx.x & 63;
    int n = blockIdx.x * 4 + wid;
    if (n >= NN) return;
    int2 r2 = rs2[n];
    int beg = __builtin_amdgcn_readfirstlane(r2.x);
    int end = __builtin_amdgcn_readfirstlane(r2.y);
    float acc = 0.f;
    int e = beg;
    for (; e + 8 <= end; e += 8) {
        unsigned v[8];
#pragma unroll
        for (int j = 0; j < 8; ++j) v[j] = em2[e + j];
        float f[8];
#pragma unroll
        for (int j = 0; j < 8; ++j)
            f[j] = bfu(fb16[(size_t)(v[j] & 0xFFFFu) * D + lane]);
#pragma unroll
        for (int j = 0; j < 8; ++j)
            acc = fmaf(__uint_as_float(v[j] & 0xFFFF0000u), f[j], acc);
    }
    for (; e + 4 <= end; e += 4) {
        unsigned v0 = em2[e], v1 = em2[e + 1], v2 = em2[e + 2], v3 = em2[e + 3];
        float f0 = bfu(fb16[(size_t)(v0 & 0xFFFFu) * D + lane]);
        float f1 = bfu(fb16[(size_t)(v1 & 0xFFFFu) * D + lane]);
        float f2 = bfu(fb16[(size_t)(v2 & 0xFFFFu) * D + lane]);
        float f3 = bfu(fb16[(size_t)(v3 & 0xFFFFu) * D + lane]);
        acc = fmaf(__uint_as_float(v0 & 0xFFFF0000u), f0, acc);
        acc = fmaf(__uint_as_float(v1 & 0xFFFF0000u), f1, acc);
        acc = fmaf(__uint_as_float(v2 & 0xFFFF0000u), f2, acc);
        acc = fmaf(__uint_as_float(v3 & 0xFFFF0000u), f3, acc);
    }
    for (; e < end; ++e) {
        unsigned v = em2[e];
        float f = bfu(fb16[(size_t)(v & 0xFFFFu) * D + lane]);
        acc = fmaf(__uint_as_float(v & 0xFFFF0000u), f, acc);
    }
    aggb[(size_t)n * D + lane] = (ushort)f2bf(__float_as_uint(acc));
}

// K4: MFMA epilogue: C[N,64] = [aggb | fb16] @ [Wn ; Ws^T] + bn, bf16 inputs,
// f32 accumulate (measured 71.2 us total, absmax 0.0625 — layouts verified).
__global__ __launch_bounds__(256) void gemm_mfma(const ushort* __restrict__ aggb,
                                                 const ushort* __restrict__ fb16,
                                                 const float* __restrict__ Wn,
                                                 const float* __restrict__ Ws,
                                                 const float* __restrict__ bn,
                                                 float* __restrict__ out) {
    __shared__ ushort Bt[64 * 136];   // 17.4 KB
    int tid = threadIdx.x;
    for (int i = tid; i < 64 * 128; i += 256) {
        int col = i & 63, k = i >> 6;
        float v = (k < 64) ? Wn[k * 64 + col] : Ws[col * 64 + (k - 64)];
        Bt[col * 136 + k] = (ushort)f2bf(__float_as_uint(v));
    }
    __syncthreads();
    int w = tid >> 6, lane = tid & 63;
    int lr = lane & 15;       // A-row / B-col / C-col within tile
    int lk = lane >> 4;       // k-subchunk 0..3
    int n0 = blockIdx.x * 128 + w * 32;
    float4v acc[2][4];
#pragma unroll
    for (int c = 0; c < 4; ++c) {
        float bv = bn[c * 16 + lr];
        acc[0][c] = (float4v){bv, bv, bv, bv};
        acc[1][c] = (float4v){bv, bv, bv, bv};
    }
    int r0 = min(n0 + lr, NN - 1);
    int r1 = min(n0 + 16 + lr, NN - 1);
#pragma unroll
    for (int kc = 0; kc < 4; ++kc) {
        const ushort* At = (kc < 2) ? aggb : fb16;
        int bk = (kc & 1) * 32 + lk * 8;       // k offset within the 64-wide table
        short8v a0 = *(const short8v*)(At + (size_t)r0 * 64 + bk);
        short8v a1 = *(const short8v*)(At + (size_t)r1 * 64 + bk);
        int kg = kc * 32 + lk * 8;             // k offset within Bt's 128
#pragma unroll
        for (int c = 0; c < 4; ++c) {
            short8v bf = *(const short8v*)(&Bt[(c * 16 + lr) * 136 + kg]);
            acc[0][c] = __builtin_amdgcn_mfma_f32_16x16x32_bf16(a0, bf, acc[0][c], 0, 0, 0);
            acc[1][c] = __builtin_amdgcn_mfma_f32_16x16x32_bf16(a1, bf, acc[1][c], 0, 0, 0);
        }
    }
#pragma unroll
    for (int r = 0; r < 2; ++r) {
        int rowb = n0 + r * 16 + lk * 4;
#pragma unroll
        for (int c = 0; c < 4; ++c) {
            int col = c * 16 + lr;
#pragma unroll
            for (int j = 0; j < 4; ++j) {
                int row = rowb + j;
                if (row < NN) out[(size_t)row * 64 + col] = acc[r][c][j];
            }
        }
    }
}

extern "C" void kernel_launch(void* const* d_in, const int* in_sizes, int n_in,
                              void* d_out, int out_size, void* d_ws, size_t ws_size,
                              hipStream_t stream) {
    const float* feat = (const float*)d_in[0];
    const int*   src  = (const int*)d_in[1];
    const int*   dst  = (const int*)d_in[2];
    const float* ew   = (const float*)d_in[3];
    const float* Wn   = (const float*)d_in[4];
    const float* bn   = (const float*)d_in[5];
    const float* Ws   = (const float*)d_in[6];
    float* out = (float*)d_out;

    char* ws = (char*)d_ws;
    uint2*    em   = (uint2*)(ws + OFF_EM);
    unsigned* em2  = (unsigned*)(ws + OFF_EM2);
    ushort*   aggb = (ushort*)(ws + OFF_AGGB);
    ushort*   fb16 = (ushort*)(ws + OFF_FB);
    int2*     rs2  = (int2*)(ws + OFF_RS2);
    int*      cur  = (int*)(ws + OFF_CUR);

    gc_zero<<<1, 256, 0, stream>>>(cur);
    bin_write<<<NWB + CONV_B, 256, 0, stream>>>(src, dst, ew, feat, cur, em, fb16);
    bucket_csr<<<NB, 256, 0, stream>>>(em, cur, rs2, em2);
    gc_gather<<<(NN + 3) / 4, 256, 0, stream>>>(fb16, rs2, em2, aggb);
    gemm_mfma<<<(NN + 127) / 128, 256, 0, stream>>>(aggb, fb16, Wn, Ws, bn, out);
}